// Round 1
// baseline (374.622 us; speedup 1.0000x reference)
//
#include <hip/hip_runtime.h>
#include <math.h>

#define BB 16
#define LL 8192
#define DD 512
#define GG 64   // blocks per batch in pass 1 (128 rows each)

typedef float vf4 __attribute__((ext_vector_type(4)));  // clang-native: OK for nontemporal builtins

__device__ __forceinline__ float dot8v(const vf4& x0, const vf4& x1, const float* qf) {
  return x0.x * qf[0] + x0.y * qf[1] + x0.z * qf[2] + x0.w * qf[3]
       + x1.x * qf[4] + x1.y * qf[5] + x1.z * qf[6] + x1.w * qf[7];
}
__device__ __forceinline__ float dot8(const float4& x0, const float4& x1, const float* qf) {
  return x0.x * qf[0] + x0.y * qf[1] + x0.z * qf[2] + x0.w * qf[3]
       + x1.x * qf[4] + x1.y * qf[5] + x1.z * qf[6] + x1.w * qf[7];
}

// ---------------- Kernel 0: q = query @ W_align^T + b_align ----------------
// 64 blocks (16 b x 4 chunks) x 512 threads. Wave-per-output-d, coalesced
// float4 W reads, 64-lane butterfly reduce.
__global__ __launch_bounds__(512) void qproj_kernel(
    const float* __restrict__ query, const float* __restrict__ Wa,
    const float* __restrict__ ba, float* __restrict__ qout) {
  const int b = blockIdx.x >> 2, chunk = blockIdx.x & 3;
  const int t = threadIdx.x;
  __shared__ float qs[DD];
  qs[t] = query[b * DD + t];
  __syncthreads();
  const int wave = t >> 6, lane = t & 63;
  float qf[8];
#pragma unroll
  for (int j = 0; j < 8; ++j) qf[j] = qs[lane * 8 + j];
  const int d0 = chunk * 128;
  for (int d = d0 + wave; d < d0 + 128; d += 8) {
    const float4* wrow = reinterpret_cast<const float4*>(Wa + (size_t)d * DD + lane * 8);
    float s = dot8(wrow[0], wrow[1], qf);
#pragma unroll
    for (int off = 32; off >= 1; off >>= 1) s += __shfl_xor(s, off, 64);
    if (lane == 0) qout[b * DD + d] = ba[d] + s;
  }
}

// ---------------- Kernel 1: online-softmax streaming pass over value -------
// Grid: BB*GG blocks x 512 threads (8 waves). Each wave owns 16 rows.
// R5 (this round): mask is ~Bernoulli(0.5) and a masked row's softmax weight
// underflows to exactly 0.0f (exp(-1e30 - M)), so masked rows are skipped
// BEFORE their 2KB value-row load is issued. Wave-uniform 16-bit survivor
// mask + ctz pair-compaction keeps the dual-row interleaved-butterfly ILP
// for surviving rows. Expected: value HBM traffic 268MB -> ~135MB, pass1
// instructions halve. [R4 8-row grouping reverted: regressed +8us,
// suspected VGPR-occupancy step from 16 live vf4 loads.]
__global__ __launch_bounds__(512) void attn_pass1(
    const float* __restrict__ value, const int* __restrict__ mask,
    const float* __restrict__ q, float* __restrict__ pc,
    float* __restrict__ pm, float* __restrict__ pl) {
  const int blk = blockIdx.x;
  const int b = blk / GG, g = blk % GG;
  const int t = threadIdx.x;
  const int wave = t >> 6, lane = t & 63;
  const int l0 = g * 128 + wave * 16;

  float qf[8];
  {
    const float4* qp = reinterpret_cast<const float4*>(q + b * DD + lane * 8);
    float4 q0 = qp[0], q1 = qp[1];
    qf[0] = q0.x; qf[1] = q0.y; qf[2] = q0.z; qf[3] = q0.w;
    qf[4] = q1.x; qf[5] = q1.y; qf[6] = q1.z; qf[7] = q1.w;
  }

  // --- wave-uniform survivor bitmask for this wave's 16 rows (64B, aligned) ---
  const int* mb = mask + b * LL;
  const int4* mp = reinterpret_cast<const int4*>(mb + l0);
  const int4 k0 = mp[0], k1 = mp[1], k2 = mp[2], k3 = mp[3];
  unsigned mbits =
        (unsigned)(k0.x != 0)        | ((unsigned)(k0.y != 0) << 1)
      | ((unsigned)(k0.z != 0) << 2) | ((unsigned)(k0.w != 0) << 3)
      | ((unsigned)(k1.x != 0) << 4) | ((unsigned)(k1.y != 0) << 5)
      | ((unsigned)(k1.z != 0) << 6) | ((unsigned)(k1.w != 0) << 7)
      | ((unsigned)(k2.x != 0) << 8) | ((unsigned)(k2.y != 0) << 9)
      | ((unsigned)(k2.z != 0) << 10)| ((unsigned)(k2.w != 0) << 11)
      | ((unsigned)(k3.x != 0) << 12)| ((unsigned)(k3.y != 0) << 13)
      | ((unsigned)(k3.z != 0) << 14)| ((unsigned)(k3.w != 0) << 15);
  unsigned rem = (~mbits) & 0xFFFFu;   // bit i set => row l0+i survives

  float m = -1e38f, ls = 0.f;
  float c[8] = {0.f, 0.f, 0.f, 0.f, 0.f, 0.f, 0.f, 0.f};
  const float* vb = value + (size_t)b * LL * DD;

  while (rem) {
    const int i0 = __builtin_ctz(rem); rem &= rem - 1u;
    int i1 = i0;
    const bool two = (rem != 0u);      // wave-uniform branch
    if (two) { i1 = __builtin_ctz(rem); rem &= rem - 1u; }
    const vf4* vp0 = reinterpret_cast<const vf4*>(vb + (size_t)(l0 + i0) * DD + lane * 8);
    const vf4* vp1 = reinterpret_cast<const vf4*>(vb + (size_t)(l0 + i1) * DD + lane * 8);
    // issue all 4 row loads up front (nontemporal: pure stream)
    vf4 a0 = __builtin_nontemporal_load(vp0);
    vf4 a1 = __builtin_nontemporal_load(vp0 + 1);
    vf4 b0 = __builtin_nontemporal_load(vp1);
    vf4 b1 = __builtin_nontemporal_load(vp1 + 1);
    float d0 = dot8v(a0, a1, qf);
    float d1 = dot8v(b0, b1, qf);
    // interleaved butterflies: two independent 6-deep chains overlap
#pragma unroll
    for (int off = 32; off >= 1; off >>= 1) {
      d0 += __shfl_xor(d0, off, 64);
      d1 += __shfl_xor(d1, off, 64);
    }
    const float s0 = d0;                       // row i0 is known unmasked
    const float s1 = two ? d1 : -1e30f;        // dummy second row: p1 -> 0
    const float mn = fmaxf(m, fmaxf(s0, s1));
    const float scale = __expf(m - mn);        // m starts -1e38 -> scale 0, no NaN
    const float p0 = __expf(s0 - mn);
    const float p1 = __expf(s1 - mn);
    ls = fmaf(ls, scale, p0 + p1);
    c[0] = fmaf(p1, b0.x, fmaf(p0, a0.x, c[0] * scale));
    c[1] = fmaf(p1, b0.y, fmaf(p0, a0.y, c[1] * scale));
    c[2] = fmaf(p1, b0.z, fmaf(p0, a0.z, c[2] * scale));
    c[3] = fmaf(p1, b0.w, fmaf(p0, a0.w, c[3] * scale));
    c[4] = fmaf(p1, b1.x, fmaf(p0, a1.x, c[4] * scale));
    c[5] = fmaf(p1, b1.y, fmaf(p0, a1.y, c[5] * scale));
    c[6] = fmaf(p1, b1.z, fmaf(p0, a1.z, c[6] * scale));
    c[7] = fmaf(p1, b1.w, fmaf(p0, a1.w, c[7] * scale));
    m = mn;
  }

  // ---- combine 8 wave partials within the block via LDS ----
  __shared__ float sc[8][DD];
  __shared__ float sm[8], sl[8];
  float4* dst = reinterpret_cast<float4*>(&sc[wave][lane * 8]);
  dst[0] = make_float4(c[0], c[1], c[2], c[3]);
  dst[1] = make_float4(c[4], c[5], c[6], c[7]);
  if (lane == 0) { sm[wave] = m; sl[wave] = ls; }
  __syncthreads();
  float M = sm[0];
#pragma unroll
  for (int w = 1; w < 8; ++w) M = fmaxf(M, sm[w]);
  float e[8];
#pragma unroll
  for (int w = 0; w < 8; ++w) e[w] = __expf(sm[w] - M);
  // one output element per thread: conflict-free LDS column reads
  float acc = 0.f;
#pragma unroll
  for (int w = 0; w < 8; ++w) acc = fmaf(sc[w][t], e[w], acc);
  pc[(size_t)(b * GG + g) * DD + t] = acc;
  if (t == 0) {
    float L = 0.f;
#pragma unroll
    for (int w = 0; w < 8; ++w) L = fmaf(sl[w], e[w], L);
    pm[b * GG + g] = M;
    pl[b * GG + g] = L;
  }
}

// ---------------- Kernel 2: combine partials + fused dual GEMV + tanh ------
// 64 blocks (16 b x 4 chunks) x 512 threads. Combine 64 block-partials ->
// context[512] in LDS, then out[b,d] = tanh(ctx@Wv[d,:]+bv[d]+q@Wq[d,:]+bq[d]).
__global__ __launch_bounds__(512) void attn_final(
    const float* __restrict__ pc, const float* __restrict__ pm,
    const float* __restrict__ pl, const float* __restrict__ q,
    const float* __restrict__ Wq, const float* __restrict__ bq,
    const float* __restrict__ Wv, const float* __restrict__ bv,
    float* __restrict__ out) {
  const int b = blockIdx.x >> 2, chunk = blockIdx.x & 3;
  const int t = threadIdx.x;
  __shared__ float ctx[DD], qs[DD];
  float M = -1e38f;
#pragma unroll 8
  for (int g = 0; g < GG; ++g) M = fmaxf(M, pm[b * GG + g]);
  float Ls = 0.f, acc = 0.f;
#pragma unroll 4
  for (int g = 0; g < GG; ++g) {
    const float e = __expf(pm[b * GG + g] - M);
    Ls += pl[b * GG + g] * e;
    acc += pc[(size_t)(b * GG + g) * DD + t] * e;
  }
  ctx[t] = acc / Ls;
  qs[t] = q[b * DD + t];
  __syncthreads();
  const int wave = t >> 6, lane = t & 63;
  float cf[8], qf[8];
#pragma unroll
  for (int j = 0; j < 8; ++j) { cf[j] = ctx[lane * 8 + j]; qf[j] = qs[lane * 8 + j]; }
  const int d0 = chunk * 128;
  for (int d = d0 + wave; d < d0 + 128; d += 8) {
    const float4* wv = reinterpret_cast<const float4*>(Wv + (size_t)d * DD + lane * 8);
    const float4* wq = reinterpret_cast<const float4*>(Wq + (size_t)d * DD + lane * 8);
    float s = dot8(wv[0], wv[1], cf) + dot8(wq[0], wq[1], qf);
#pragma unroll
    for (int off = 32; off >= 1; off >>= 1) s += __shfl_xor(s, off, 64);
    if (lane == 0) out[b * DD + d] = tanhf(s + bv[d] + bq[d]);
  }
}

extern "C" void kernel_launch(void* const* d_in, const int* in_sizes, int n_in,
                              void* d_out, int out_size, void* d_ws, size_t ws_size,
                              hipStream_t stream) {
  const float* query = (const float*)d_in[0];
  const float* value = (const float*)d_in[1];
  const int*   mask  = (const int*)d_in[2];
  const float* Wa    = (const float*)d_in[3];
  const float* ba    = (const float*)d_in[4];
  const float* Wq    = (const float*)d_in[5];
  const float* bq    = (const float*)d_in[6];
  const float* Wv    = (const float*)d_in[7];
  const float* bv    = (const float*)d_in[8];
  float* out = (float*)d_out;

  float* ws = (float*)d_ws;
  float* qbuf = ws;                         // BB*DD    = 8192 floats
  float* pc   = qbuf + BB * DD;             // BB*GG*DD = 524288 floats
  float* pm   = pc + (size_t)BB * GG * DD;  // BB*GG    = 1024 floats
  float* pl   = pm + BB * GG;               // BB*GG    = 1024 floats

  qproj_kernel<<<BB * 4, 512, 0, stream>>>(query, Wa, ba, qbuf);
  attn_pass1<<<BB * GG, 512, 0, stream>>>(value, mask, qbuf, pc, pm, pl);
  attn_final<<<BB * 4, 512, 0, stream>>>(pc, pm, pl, qbuf, Wq, bq, Wv, bv, out);
}

// Round 2
// 352.688 us; speedup vs baseline: 1.0622x; 1.0622x over previous
//
#include <hip/hip_runtime.h>
#include <math.h>

#define BB 16
#define LL 8192
#define DD 512
#define GG 64   // blocks per batch in pass 1 (128 rows each)

typedef float vf4 __attribute__((ext_vector_type(4)));  // clang-native: OK for nontemporal builtins

__device__ __forceinline__ float dot8v(const vf4& x0, const vf4& x1, const float* qf) {
  return x0.x * qf[0] + x0.y * qf[1] + x0.z * qf[2] + x0.w * qf[3]
       + x1.x * qf[4] + x1.y * qf[5] + x1.z * qf[6] + x1.w * qf[7];
}
__device__ __forceinline__ float dot8(const float4& x0, const float4& x1, const float* qf) {
  return x0.x * qf[0] + x0.y * qf[1] + x0.z * qf[2] + x0.w * qf[3]
       + x1.x * qf[4] + x1.y * qf[5] + x1.z * qf[6] + x1.w * qf[7];
}

// ---------------- Kernel 0: q = query @ W_align^T + b_align ----------------
// R6: 256 blocks (16 b x 16 chunks of 32 d) x 512 threads -> all 256 CUs,
// 4 GEMV iters/wave instead of 16 (was 64 blocks = 64 CUs, latency-chained).
__global__ __launch_bounds__(512) void qproj_kernel(
    const float* __restrict__ query, const float* __restrict__ Wa,
    const float* __restrict__ ba, float* __restrict__ qout) {
  const int b = blockIdx.x >> 4, chunk = blockIdx.x & 15;
  const int t = threadIdx.x;
  __shared__ float qs[DD];
  qs[t] = query[b * DD + t];
  __syncthreads();
  const int wave = t >> 6, lane = t & 63;
  float qf[8];
#pragma unroll
  for (int j = 0; j < 8; ++j) qf[j] = qs[lane * 8 + j];
  const int d0 = chunk * 32;
#pragma unroll
  for (int d = d0 + wave; d < d0 + 32; d += 8) {
    const float4* wrow = reinterpret_cast<const float4*>(Wa + (size_t)d * DD + lane * 8);
    float s = dot8(wrow[0], wrow[1], qf);
#pragma unroll
    for (int off = 32; off >= 1; off >>= 1) s += __shfl_xor(s, off, 64);
    if (lane == 0) qout[b * DD + d] = ba[d] + s;
  }
}

// ---------------- Kernel 1: online-softmax streaming pass over value -------
// Grid: BB*GG blocks x 512 threads (8 waves). Each wave owns 16 rows.
// R5: mask is ~Bernoulli(0.5) and a masked row's softmax weight underflows
// to exactly 0.0f (exp(-1e30 - M)), so masked rows are skipped BEFORE their
// 2KB value-row load is issued (wave-uniform 16-bit survivor mask + ctz
// pair-compaction). Confirmed R1: dur -18us, consistent with pass1 running
// ~5.3 TB/s on the surviving ~134 MB. Left untouched this round (BW-bound;
// R4's 8-row grouping showed extra in-flight vf4s cost occupancy).
__global__ __launch_bounds__(512) void attn_pass1(
    const float* __restrict__ value, const int* __restrict__ mask,
    const float* __restrict__ q, float* __restrict__ pc,
    float* __restrict__ pm, float* __restrict__ pl) {
  const int blk = blockIdx.x;
  const int b = blk / GG, g = blk % GG;
  const int t = threadIdx.x;
  const int wave = t >> 6, lane = t & 63;
  const int l0 = g * 128 + wave * 16;

  float qf[8];
  {
    const float4* qp = reinterpret_cast<const float4*>(q + b * DD + lane * 8);
    float4 q0 = qp[0], q1 = qp[1];
    qf[0] = q0.x; qf[1] = q0.y; qf[2] = q0.z; qf[3] = q0.w;
    qf[4] = q1.x; qf[5] = q1.y; qf[6] = q1.z; qf[7] = q1.w;
  }

  // --- wave-uniform survivor bitmask for this wave's 16 rows (64B, aligned) ---
  const int* mb = mask + b * LL;
  const int4* mp = reinterpret_cast<const int4*>(mb + l0);
  const int4 k0 = mp[0], k1 = mp[1], k2 = mp[2], k3 = mp[3];
  unsigned mbits =
        (unsigned)(k0.x != 0)        | ((unsigned)(k0.y != 0) << 1)
      | ((unsigned)(k0.z != 0) << 2) | ((unsigned)(k0.w != 0) << 3)
      | ((unsigned)(k1.x != 0) << 4) | ((unsigned)(k1.y != 0) << 5)
      | ((unsigned)(k1.z != 0) << 6) | ((unsigned)(k1.w != 0) << 7)
      | ((unsigned)(k2.x != 0) << 8) | ((unsigned)(k2.y != 0) << 9)
      | ((unsigned)(k2.z != 0) << 10)| ((unsigned)(k2.w != 0) << 11)
      | ((unsigned)(k3.x != 0) << 12)| ((unsigned)(k3.y != 0) << 13)
      | ((unsigned)(k3.z != 0) << 14)| ((unsigned)(k3.w != 0) << 15);
  unsigned rem = (~mbits) & 0xFFFFu;   // bit i set => row l0+i survives

  float m = -1e38f, ls = 0.f;
  float c[8] = {0.f, 0.f, 0.f, 0.f, 0.f, 0.f, 0.f, 0.f};
  const float* vb = value + (size_t)b * LL * DD;

  while (rem) {
    const int i0 = __builtin_ctz(rem); rem &= rem - 1u;
    int i1 = i0;
    const bool two = (rem != 0u);      // wave-uniform branch
    if (two) { i1 = __builtin_ctz(rem); rem &= rem - 1u; }
    const vf4* vp0 = reinterpret_cast<const vf4*>(vb + (size_t)(l0 + i0) * DD + lane * 8);
    const vf4* vp1 = reinterpret_cast<const vf4*>(vb + (size_t)(l0 + i1) * DD + lane * 8);
    // issue all 4 row loads up front (nontemporal: pure stream)
    vf4 a0 = __builtin_nontemporal_load(vp0);
    vf4 a1 = __builtin_nontemporal_load(vp0 + 1);
    vf4 b0 = __builtin_nontemporal_load(vp1);
    vf4 b1 = __builtin_nontemporal_load(vp1 + 1);
    float d0 = dot8v(a0, a1, qf);
    float d1 = dot8v(b0, b1, qf);
    // interleaved butterflies: two independent 6-deep chains overlap
#pragma unroll
    for (int off = 32; off >= 1; off >>= 1) {
      d0 += __shfl_xor(d0, off, 64);
      d1 += __shfl_xor(d1, off, 64);
    }
    const float s0 = d0;                       // row i0 is known unmasked
    const float s1 = two ? d1 : -1e30f;        // dummy second row: p1 -> 0
    const float mn = fmaxf(m, fmaxf(s0, s1));
    const float scale = __expf(m - mn);        // m starts -1e38 -> scale 0, no NaN
    const float p0 = __expf(s0 - mn);
    const float p1 = __expf(s1 - mn);
    ls = fmaf(ls, scale, p0 + p1);
    c[0] = fmaf(p1, b0.x, fmaf(p0, a0.x, c[0] * scale));
    c[1] = fmaf(p1, b0.y, fmaf(p0, a0.y, c[1] * scale));
    c[2] = fmaf(p1, b0.z, fmaf(p0, a0.z, c[2] * scale));
    c[3] = fmaf(p1, b0.w, fmaf(p0, a0.w, c[3] * scale));
    c[4] = fmaf(p1, b1.x, fmaf(p0, a1.x, c[4] * scale));
    c[5] = fmaf(p1, b1.y, fmaf(p0, a1.y, c[5] * scale));
    c[6] = fmaf(p1, b1.z, fmaf(p0, a1.z, c[6] * scale));
    c[7] = fmaf(p1, b1.w, fmaf(p0, a1.w, c[7] * scale));
    m = mn;
  }

  // ---- combine 8 wave partials within the block via LDS ----
  __shared__ float sc[8][DD];
  __shared__ float sm[8], sl[8];
  float4* dst = reinterpret_cast<float4*>(&sc[wave][lane * 8]);
  dst[0] = make_float4(c[0], c[1], c[2], c[3]);
  dst[1] = make_float4(c[4], c[5], c[6], c[7]);
  if (lane == 0) { sm[wave] = m; sl[wave] = ls; }
  __syncthreads();
  float M = sm[0];
#pragma unroll
  for (int w = 1; w < 8; ++w) M = fmaxf(M, sm[w]);
  float e[8];
#pragma unroll
  for (int w = 0; w < 8; ++w) e[w] = __expf(sm[w] - M);
  // one output element per thread: conflict-free LDS column reads
  float acc = 0.f;
#pragma unroll
  for (int w = 0; w < 8; ++w) acc = fmaf(sc[w][t], e[w], acc);
  pc[(size_t)(b * GG + g) * DD + t] = acc;
  if (t == 0) {
    float L = 0.f;
#pragma unroll
    for (int w = 0; w < 8; ++w) L = fmaf(sl[w], e[w], L);
    pm[b * GG + g] = M;
    pl[b * GG + g] = L;
  }
}

// ---------------- Kernel 2: combine partials + fused dual GEMV + tanh ------
// R6: 256 blocks (16 b x 16 chunks of 32 d) x 512 threads (was 64 blocks).
// Combine phase: 4 independent accumulators break the 64-deep serial fma
// chain over L2-latency pc loads. Extra pc re-reads (4x) are L2-resident.
__global__ __launch_bounds__(512) void attn_final(
    const float* __restrict__ pc, const float* __restrict__ pm,
    const float* __restrict__ pl, const float* __restrict__ q,
    const float* __restrict__ Wq, const float* __restrict__ bq,
    const float* __restrict__ Wv, const float* __restrict__ bv,
    float* __restrict__ out) {
  const int b = blockIdx.x >> 4, chunk = blockIdx.x & 15;
  const int t = threadIdx.x;
  __shared__ float ctx[DD], qs[DD];
  float M = -1e38f;
#pragma unroll 8
  for (int g = 0; g < GG; ++g) M = fmaxf(M, pm[b * GG + g]);
  float Ls = 0.f, a0 = 0.f, a1 = 0.f, a2 = 0.f, a3 = 0.f;
#pragma unroll 4
  for (int g = 0; g < GG; g += 4) {
    const float e0 = __expf(pm[b * GG + g + 0] - M);
    const float e1 = __expf(pm[b * GG + g + 1] - M);
    const float e2 = __expf(pm[b * GG + g + 2] - M);
    const float e3 = __expf(pm[b * GG + g + 3] - M);
    Ls += pl[b * GG + g + 0] * e0 + pl[b * GG + g + 1] * e1
        + pl[b * GG + g + 2] * e2 + pl[b * GG + g + 3] * e3;
    a0 = fmaf(pc[(size_t)(b * GG + g + 0) * DD + t], e0, a0);
    a1 = fmaf(pc[(size_t)(b * GG + g + 1) * DD + t], e1, a1);
    a2 = fmaf(pc[(size_t)(b * GG + g + 2) * DD + t], e2, a2);
    a3 = fmaf(pc[(size_t)(b * GG + g + 3) * DD + t], e3, a3);
  }
  ctx[t] = ((a0 + a1) + (a2 + a3)) / Ls;
  qs[t] = q[b * DD + t];
  __syncthreads();
  const int wave = t >> 6, lane = t & 63;
  float cf[8], qf[8];
#pragma unroll
  for (int j = 0; j < 8; ++j) { cf[j] = ctx[lane * 8 + j]; qf[j] = qs[lane * 8 + j]; }
  const int d0 = chunk * 32;
#pragma unroll
  for (int d = d0 + wave; d < d0 + 32; d += 8) {
    const float4* wv = reinterpret_cast<const float4*>(Wv + (size_t)d * DD + lane * 8);
    const float4* wq = reinterpret_cast<const float4*>(Wq + (size_t)d * DD + lane * 8);
    float s = dot8(wv[0], wv[1], cf) + dot8(wq[0], wq[1], qf);
#pragma unroll
    for (int off = 32; off >= 1; off >>= 1) s += __shfl_xor(s, off, 64);
    if (lane == 0) out[b * DD + d] = tanhf(s + bv[d] + bq[d]);
  }
}

extern "C" void kernel_launch(void* const* d_in, const int* in_sizes, int n_in,
                              void* d_out, int out_size, void* d_ws, size_t ws_size,
                              hipStream_t stream) {
  const float* query = (const float*)d_in[0];
  const float* value = (const float*)d_in[1];
  const int*   mask  = (const int*)d_in[2];
  const float* Wa    = (const float*)d_in[3];
  const float* ba    = (const float*)d_in[4];
  const float* Wq    = (const float*)d_in[5];
  const float* bq    = (const float*)d_in[6];
  const float* Wv    = (const float*)d_in[7];
  const float* bv    = (const float*)d_in[8];
  float* out = (float*)d_out;

  float* ws = (float*)d_ws;
  float* qbuf = ws;                         // BB*DD    = 8192 floats
  float* pc   = qbuf + BB * DD;             // BB*GG*DD = 524288 floats
  float* pm   = pc + (size_t)BB * GG * DD;  // BB*GG    = 1024 floats
  float* pl   = pm + BB * GG;               // BB*GG    = 1024 floats

  qproj_kernel<<<BB * 16, 512, 0, stream>>>(query, Wa, ba, qbuf);
  attn_pass1<<<BB * GG, 512, 0, stream>>>(value, mask, qbuf, pc, pm, pl);
  attn_final<<<BB * 16, 512, 0, stream>>>(pc, pm, pl, qbuf, Wq, bq, Wv, bv, out);
}